// Round 1
// baseline (202.596 us; speedup 1.0000x reference)
//
#include <hip/hip_runtime.h>

#define NB 4
#define SEQ 4096
#define DIMK 1024
#define DKV 128
#define SCALE 0.08838834764831845f   // 1/sqrt(128)

typedef float  f32x4 __attribute__((ext_vector_type(4)));
typedef _Float16 f16x8 __attribute__((ext_vector_type(8)));

// ---------------- kernel 0: transpose W -> f16 WT[3][128][1024] ----------------
__global__ void prep_wt(const float* __restrict__ Wq, const float* __restrict__ Wk,
                        const float* __restrict__ Wv, _Float16* __restrict__ WT) {
    int tid = blockIdx.x * 256 + threadIdx.x;        // 3*1024*128 = 393216 threads
    int n  = tid & 127;
    int k  = (tid >> 7) & 1023;
    int w3 = tid >> 17;
    const float* W = (w3 == 0) ? Wq : (w3 == 1) ? Wk : Wv;
    WT[((size_t)w3 * 128 + n) * 1024 + k] = (_Float16)W[(size_t)k * 128 + n];
}

// ---------------- kernel 1: QKV projection ----------------
// block: 256 thr (4 waves), computes 64 rows x 128 cols for q,k,v
// LDS: WTs[3*128][40] f16 (pad 32->40, 80B rows, 16B aligned)
__global__ __launch_bounds__(256) void qkv_proj(
    const float* __restrict__ X,
    const float* __restrict__ bq, const float* __restrict__ bk, const float* __restrict__ bv,
    const _Float16* __restrict__ WT,
    _Float16* __restrict__ Qh, _Float16* __restrict__ Kh, _Float16* __restrict__ VTh) {

    __shared__ __attribute__((aligned(16))) _Float16 WTs[3 * 128 * 40];
    const int t = threadIdx.x;
    const int w = t >> 6, l = t & 63;
    const int lrow = l & 15, lg = l >> 4;
    const int r0 = blockIdx.x * 64;

    f32x4 acc[3][8] = {};
    const float* xrow = X + (size_t)(r0 + w * 16 + lrow) * DIMK;

    for (int k0 = 0; k0 < DIMK; k0 += 32) {
        __syncthreads();
        // stage WT tile: 384 rows x 32 f16 = 1536 x 16B chunks
        #pragma unroll
        for (int i = 0; i < 6; ++i) {
            int c = t + 256 * i;
            int row = c >> 2, part = c & 3;
            *(int4*)((char*)WTs + row * 80 + part * 16) =
                *(const int4*)(WT + (size_t)row * 1024 + k0 + part * 8);
        }
        __syncthreads();
        // A fragment from global fp32, convert to f16
        f16x8 a;
        const float* xp = xrow + k0 + lg * 8;
        float4 x0 = *(const float4*)(xp);
        float4 x1 = *(const float4*)(xp + 4);
        a[0] = (_Float16)x0.x; a[1] = (_Float16)x0.y; a[2] = (_Float16)x0.z; a[3] = (_Float16)x0.w;
        a[4] = (_Float16)x1.x; a[5] = (_Float16)x1.y; a[6] = (_Float16)x1.z; a[7] = (_Float16)x1.w;

        #pragma unroll
        for (int w3 = 0; w3 < 3; ++w3)
            #pragma unroll
            for (int n = 0; n < 8; ++n) {
                f16x8 bf = *(const f16x8*)((const char*)WTs + (w3 * 128 + n * 16 + lrow) * 80 + lg * 16);
                acc[w3][n] = __builtin_amdgcn_mfma_f32_16x16x32_f16(a, bf, acc[w3][n], 0, 0, 0);
            }
    }
    // epilogue: C layout col = lane&15, row = (lane>>4)*4 + j
    #pragma unroll
    for (int n = 0; n < 8; ++n) {
        int col = n * 16 + lrow;
        float bqv = bq[col], bkv = bk[col], bvv = bv[col];
        #pragma unroll
        for (int j = 0; j < 4; ++j) {
            int grow = r0 + w * 16 + lg * 4 + j;
            Qh[(size_t)grow * DKV + col] = (_Float16)((acc[0][n][j] + bqv) * SCALE);
            Kh[(size_t)grow * DKV + col] = (_Float16)(acc[1][n][j] + bkv);
            int b = grow >> 12, sp = grow & 4095;
            VTh[((size_t)b * DKV + col) * SEQ + sp] = (_Float16)(acc[2][n][j] + bvv);
        }
    }
}

// ---------------- kernel 2: flash attention ----------------
// block: 256 thr (4 waves), 64 q-rows; loop over 64-key tiles
#define LDK 136   // Ks row stride in f16 (272B)
#define LDV 72    // VTs row stride (144B)
#define LDP 72    // Ps row stride (144B)

__global__ __launch_bounds__(256) void attn_kernel(
    const _Float16* __restrict__ Qh, const _Float16* __restrict__ Kh,
    const _Float16* __restrict__ VTh, float* __restrict__ out) {

    __shared__ __attribute__((aligned(16))) _Float16 Ks[64 * LDK];
    __shared__ __attribute__((aligned(16))) _Float16 VTs[128 * LDV];
    __shared__ __attribute__((aligned(16))) _Float16 Ps[4 * 16 * LDP];

    const int t = threadIdx.x;
    const int w = t >> 6, l = t & 63;
    const int lrow = l & 15, lg = l >> 4;
    const int b  = blockIdx.x >> 6;
    const int qt = blockIdx.x & 63;
    const int qrow = b * SEQ + qt * 64 + w * 16 + lrow;

    // Q fragments held in registers for the whole kernel
    f16x8 qfrag[4];
    #pragma unroll
    for (int ds = 0; ds < 4; ++ds)
        qfrag[ds] = *(const f16x8*)(Qh + (size_t)qrow * DKV + ds * 32 + lg * 8);

    f32x4 o[8] = {};
    float mrun[4] = {-INFINITY, -INFINITY, -INFINITY, -INFINITY};
    float lrun[4] = {0.f, 0.f, 0.f, 0.f};

    for (int kt = 0; kt < 64; ++kt) {
        const int k0 = kt * 64;
        __syncthreads();
        // stage K tile: 64 rows x 128 f16
        #pragma unroll
        for (int i = 0; i < 4; ++i) {
            int c = t + 256 * i; int row = c >> 4, part = c & 15;
            *(int4*)((char*)Ks + row * (2 * LDK) + part * 16) =
                *(const int4*)(Kh + (size_t)(b * SEQ + k0 + row) * DKV + part * 8);
        }
        // stage V^T tile: 128 rows x 64 f16
        #pragma unroll
        for (int i = 0; i < 4; ++i) {
            int c = t + 256 * i; int dv = c >> 3, part = c & 7;
            *(int4*)((char*)VTs + dv * (2 * LDV) + part * 16) =
                *(const int4*)(VTh + (size_t)(b * DKV + dv) * SEQ + k0 + part * 8);
        }
        __syncthreads();

        // S = Q K^T  (scale pre-folded into Q)
        f32x4 sacc[4] = {};
        #pragma unroll
        for (int n = 0; n < 4; ++n)
            #pragma unroll
            for (int ds = 0; ds < 4; ++ds) {
                f16x8 kf = *(const f16x8*)((const char*)Ks + (n * 16 + lrow) * (2 * LDK) + ds * 64 + lg * 16);
                sacc[n] = __builtin_amdgcn_mfma_f32_16x16x32_f16(qfrag[ds], kf, sacc[n], 0, 0, 0);
            }

        // online softmax: row j lives on 16 lanes sharing lg, spread over lrow & n
        float mt[4], p[4][4], ls[4];
        #pragma unroll
        for (int j = 0; j < 4; ++j)
            mt[j] = fmaxf(fmaxf(sacc[0][j], sacc[1][j]), fmaxf(sacc[2][j], sacc[3][j]));
        #pragma unroll
        for (int off = 1; off <= 8; off <<= 1)
            #pragma unroll
            for (int j = 0; j < 4; ++j)
                mt[j] = fmaxf(mt[j], __shfl_xor(mt[j], off));

        #pragma unroll
        for (int j = 0; j < 4; ++j) {
            float mnew = fmaxf(mrun[j], mt[j]);
            float corr = __expf(mrun[j] - mnew);
            mrun[j] = mnew;
            ls[j] = 0.f;
            #pragma unroll
            for (int n = 0; n < 4; ++n) { p[n][j] = __expf(sacc[n][j] - mnew); ls[j] += p[n][j]; }
            #pragma unroll
            for (int n = 0; n < 8; ++n) o[n][j] *= corr;
            lrun[j] *= corr;
        }
        #pragma unroll
        for (int off = 1; off <= 8; off <<= 1)
            #pragma unroll
            for (int j = 0; j < 4; ++j)
                ls[j] += __shfl_xor(ls[j], off);
        #pragma unroll
        for (int j = 0; j < 4; ++j) lrun[j] += ls[j];

        // write P to LDS in C-layout, reread as A-fragments
        #pragma unroll
        for (int n = 0; n < 4; ++n)
            #pragma unroll
            for (int j = 0; j < 4; ++j)
                *((_Float16*)((char*)Ps + (w * 16 + lg * 4 + j) * (2 * LDP) + (n * 16 + lrow) * 2)) =
                    (_Float16)p[n][j];
        __syncthreads();

        // O += P V
        f16x8 pf[2];
        #pragma unroll
        for (int ks = 0; ks < 2; ++ks)
            pf[ks] = *(const f16x8*)((const char*)Ps + (w * 16 + lrow) * (2 * LDP) + ks * 64 + lg * 16);
        #pragma unroll
        for (int n = 0; n < 8; ++n)
            #pragma unroll
            for (int ks = 0; ks < 2; ++ks) {
                f16x8 vf = *(const f16x8*)((const char*)VTs + (n * 16 + lrow) * (2 * LDV) + ks * 64 + lg * 16);
                o[n] = __builtin_amdgcn_mfma_f32_16x16x32_f16(pf[ks], vf, o[n], 0, 0, 0);
            }
    }

    // epilogue
    float rl[4];
    #pragma unroll
    for (int j = 0; j < 4; ++j) rl[j] = 1.0f / lrun[j];
    const size_t obase = (size_t)(b * SEQ + qt * 64 + w * 16) * DKV;
    #pragma unroll
    for (int n = 0; n < 8; ++n)
        #pragma unroll
        for (int j = 0; j < 4; ++j)
            out[obase + (size_t)(lg * 4 + j) * DKV + n * 16 + lrow] = o[n][j] * rl[j];
}

extern "C" void kernel_launch(void* const* d_in, const int* in_sizes, int n_in,
                              void* d_out, int out_size, void* d_ws, size_t ws_size,
                              hipStream_t stream) {
    const float* X  = (const float*)d_in[0];
    const float* Wq = (const float*)d_in[1];
    const float* bq = (const float*)d_in[2];
    const float* Wk = (const float*)d_in[3];
    const float* bk = (const float*)d_in[4];
    const float* Wv = (const float*)d_in[5];
    const float* bv = (const float*)d_in[6];
    float* out = (float*)d_out;

    _Float16* Qh  = (_Float16*)d_ws;                       // [B*S][128]
    _Float16* Kh  = Qh  + (size_t)NB * SEQ * DKV;          // [B*S][128]
    _Float16* VTh = Kh  + (size_t)NB * SEQ * DKV;          // [B][128][S]
    _Float16* WTh = VTh + (size_t)NB * SEQ * DKV;          // [3][128][1024]

    prep_wt<<<(3 * 1024 * 128) / 256, 256, 0, stream>>>(Wq, Wk, Wv, WTh);
    qkv_proj<<<(NB * SEQ) / 64, 256, 0, stream>>>(X, bq, bk, bv, WTh, Qh, Kh, VTh);
    attn_kernel<<<NB * (SEQ / 64), 256, 0, stream>>>(Qh, Kh, VTh, out);
}

// Round 2
// 154.104 us; speedup vs baseline: 1.3147x; 1.3147x over previous
//
#include <hip/hip_runtime.h>

#define NB 4
#define SEQ 4096
#define DIMK 1024
#define DKV 128
#define SCALE 0.08838834764831845f   // 1/sqrt(128)

typedef float  f32x4 __attribute__((ext_vector_type(4)));
typedef _Float16 f16x8 __attribute__((ext_vector_type(8)));

// ---------------- kernel 0: transpose W -> f16 WT[3][128][1024] ----------------
__global__ void prep_wt(const float* __restrict__ Wq, const float* __restrict__ Wk,
                        const float* __restrict__ Wv, _Float16* __restrict__ WT) {
    int tid = blockIdx.x * 256 + threadIdx.x;        // 3*1024*128 = 393216 threads
    int n  = tid & 127;
    int k  = (tid >> 7) & 1023;
    int w3 = tid >> 17;
    const float* W = (w3 == 0) ? Wq : (w3 == 1) ? Wk : Wv;
    WT[((size_t)w3 * 128 + n) * 1024 + k] = (_Float16)W[(size_t)k * 128 + n];
}

// ---------------- kernel 1: QKV projection, w3-split ----------------
// grid = 256 row-tiles * 3 (q,k,v); block 256 thr (4 waves); 64 rows x 128 cols out
__global__ __launch_bounds__(256) void qkv_proj(
    const float* __restrict__ X,
    const float* __restrict__ bq, const float* __restrict__ bk, const float* __restrict__ bv,
    const _Float16* __restrict__ WT,
    _Float16* __restrict__ Qh, _Float16* __restrict__ Kh, _Float16* __restrict__ VTh) {

    __shared__ __attribute__((aligned(16))) _Float16 WTs[128 * 40];
    const int t = threadIdx.x;
    const int w = t >> 6, l = t & 63;
    const int lrow = l & 15, lg = l >> 4;
    const int w3   = blockIdx.x % 3;       // adjacent blocks share the X tile
    const int tile = blockIdx.x / 3;
    const int r0 = tile * 64;

    f32x4 acc[8] = {};
    const float* xrow = X + (size_t)(r0 + w * 16 + lrow) * DIMK;
    const _Float16* Wbase = WT + (size_t)w3 * 128 * 1024;

    for (int k0 = 0; k0 < DIMK; k0 += 32) {
        __syncthreads();
        // stage 128 rows x 32 f16 of W-slice: 512 16B chunks
        #pragma unroll
        for (int i = 0; i < 2; ++i) {
            int c = t + 256 * i;
            int row = c >> 2, part = c & 3;
            *(int4*)((char*)WTs + row * 80 + part * 16) =
                *(const int4*)(Wbase + (size_t)row * 1024 + k0 + part * 8);
        }
        __syncthreads();
        f16x8 a;
        const float* xp = xrow + k0 + lg * 8;
        float4 x0 = *(const float4*)(xp);
        float4 x1 = *(const float4*)(xp + 4);
        a[0] = (_Float16)x0.x; a[1] = (_Float16)x0.y; a[2] = (_Float16)x0.z; a[3] = (_Float16)x0.w;
        a[4] = (_Float16)x1.x; a[5] = (_Float16)x1.y; a[6] = (_Float16)x1.z; a[7] = (_Float16)x1.w;

        #pragma unroll
        for (int n = 0; n < 8; ++n) {
            f16x8 bf = *(const f16x8*)((const char*)WTs + (n * 16 + lrow) * 80 + lg * 16);
            acc[n] = __builtin_amdgcn_mfma_f32_16x16x32_f16(a, bf, acc[n], 0, 0, 0);
        }
    }
    const float* bias = (w3 == 0) ? bq : (w3 == 1) ? bk : bv;
    #pragma unroll
    for (int n = 0; n < 8; ++n) {
        int col = n * 16 + lrow;
        float bv_ = bias[col];
        #pragma unroll
        for (int j = 0; j < 4; ++j) {
            int grow = r0 + w * 16 + lg * 4 + j;
            float val = acc[n][j] + bv_;
            if (w3 == 0) {
                Qh[(size_t)grow * DKV + col] = (_Float16)(val * SCALE);
            } else if (w3 == 1) {
                Kh[(size_t)grow * DKV + col] = (_Float16)val;
            } else {
                int b = grow >> 12, sp = grow & 4095;
                VTh[((size_t)b * DKV + col) * SEQ + sp] = (_Float16)val;
            }
        }
    }
}

// ---------------- kernel 2: flash attention with KV-split ----------------
// block: 256 thr (4 waves), 64 q-rows, keys [s*kps, (s+1)*kps)
// LDS (swizzled, no pad): Ks 64x128 f16 (16KB) + VTs 128x64 (16KB) + Ps 64x64 (8KB) = 40960B
__global__ __launch_bounds__(256) void attn_kernel(
    const _Float16* __restrict__ Qh, const _Float16* __restrict__ Kh,
    const _Float16* __restrict__ VTh, float* __restrict__ out,
    float* __restrict__ Opart, float* __restrict__ Mp, float* __restrict__ Lp,
    int nsplit, int kps) {

    __shared__ __attribute__((aligned(16))) _Float16 Ks[64 * 128];
    __shared__ __attribute__((aligned(16))) _Float16 VTs[128 * 64];
    __shared__ __attribute__((aligned(16))) _Float16 Ps[64 * 64];

    const int t = threadIdx.x;
    const int w = t >> 6, l = t & 63;
    const int lrow = l & 15, lg = l >> 4;
    const int bid = blockIdx.x;
    const int b   = bid / (64 * nsplit);
    const int rem = bid % (64 * nsplit);
    const int s   = rem / 64;          // kv-split index; 64 q-tiles share a key range
    const int qt  = rem % 64;
    const int qrow = b * SEQ + qt * 64 + w * 16 + lrow;

    f16x8 qfrag[4];
    #pragma unroll
    for (int ds = 0; ds < 4; ++ds)
        qfrag[ds] = *(const f16x8*)(Qh + (size_t)qrow * DKV + ds * 32 + lg * 8);

    f32x4 o[8] = {};
    float mrun[4] = {-INFINITY, -INFINITY, -INFINITY, -INFINITY};
    float lrun[4] = {0.f, 0.f, 0.f, 0.f};

    const int kts = kps >> 6;
    for (int kt = 0; kt < kts; ++kt) {
        const int k0 = s * kps + kt * 64;
        __syncthreads();
        // stage K tile 64x128 f16, XOR-swizzled: byte ^= (row&7)<<4
        #pragma unroll
        for (int i = 0; i < 4; ++i) {
            int c = t + 256 * i; int row = c >> 4, part = c & 15;
            *(int4*)((char*)Ks + row * 256 + ((part * 16) ^ ((row & 7) << 4))) =
                *(const int4*)(Kh + (size_t)(b * SEQ + k0 + row) * DKV + part * 8);
        }
        // stage V^T tile 128x64 f16, swizzled
        #pragma unroll
        for (int i = 0; i < 4; ++i) {
            int c = t + 256 * i; int dv = c >> 3, part = c & 7;
            *(int4*)((char*)VTs + dv * 128 + ((part * 16) ^ ((dv & 7) << 4))) =
                *(const int4*)(VTh + (size_t)(b * DKV + dv) * SEQ + k0 + part * 8);
        }
        __syncthreads();

        // S = Q K^T (scale folded into Q)
        f32x4 sacc[4] = {};
        #pragma unroll
        for (int n = 0; n < 4; ++n) {
            int rn = n * 16 + lrow;
            #pragma unroll
            for (int ds = 0; ds < 4; ++ds) {
                f16x8 kf = *(const f16x8*)((const char*)Ks + rn * 256 +
                                           ((ds * 64 + lg * 16) ^ ((rn & 7) << 4)));
                sacc[n] = __builtin_amdgcn_mfma_f32_16x16x32_f16(qfrag[ds], kf, sacc[n], 0, 0, 0);
            }
        }

        // online softmax
        float mt[4], p[4][4], ls[4];
        #pragma unroll
        for (int j = 0; j < 4; ++j)
            mt[j] = fmaxf(fmaxf(sacc[0][j], sacc[1][j]), fmaxf(sacc[2][j], sacc[3][j]));
        #pragma unroll
        for (int off = 1; off <= 8; off <<= 1)
            #pragma unroll
            for (int j = 0; j < 4; ++j)
                mt[j] = fmaxf(mt[j], __shfl_xor(mt[j], off));

        #pragma unroll
        for (int j = 0; j < 4; ++j) {
            float mnew = fmaxf(mrun[j], mt[j]);
            float corr = __expf(mrun[j] - mnew);
            mrun[j] = mnew;
            ls[j] = 0.f;
            #pragma unroll
            for (int n = 0; n < 4; ++n) { p[n][j] = __expf(sacc[n][j] - mnew); ls[j] += p[n][j]; }
            #pragma unroll
            for (int n = 0; n < 8; ++n) o[n][j] *= corr;
            lrun[j] *= corr;
        }
        #pragma unroll
        for (int off = 1; off <= 8; off <<= 1)
            #pragma unroll
            for (int j = 0; j < 4; ++j)
                ls[j] += __shfl_xor(ls[j], off);
        #pragma unroll
        for (int j = 0; j < 4; ++j) lrun[j] += ls[j];

        // P -> LDS (swizzled rows of 128B)
        #pragma unroll
        for (int n = 0; n < 4; ++n)
            #pragma unroll
            for (int j = 0; j < 4; ++j) {
                int row = w * 16 + lg * 4 + j;
                *((_Float16*)((char*)Ps + row * 128 +
                              (((n * 16 + lrow) * 2) ^ ((row & 7) << 4)))) = (_Float16)p[n][j];
            }
        __syncthreads();

        // O += P V
        int prow = w * 16 + lrow;
        f16x8 pf[2];
        #pragma unroll
        for (int ks = 0; ks < 2; ++ks)
            pf[ks] = *(const f16x8*)((const char*)Ps + prow * 128 +
                                     ((ks * 64 + lg * 16) ^ ((prow & 7) << 4)));
        #pragma unroll
        for (int n = 0; n < 8; ++n) {
            int rv = n * 16 + lrow;
            #pragma unroll
            for (int ks = 0; ks < 2; ++ks) {
                f16x8 vf = *(const f16x8*)((const char*)VTs + rv * 128 +
                                           ((ks * 64 + lg * 16) ^ ((rv & 7) << 4)));
                o[n] = __builtin_amdgcn_mfma_f32_16x16x32_f16(pf[ks], vf, o[n], 0, 0, 0);
            }
        }
    }

    if (nsplit == 1) {
        float rl[4];
        #pragma unroll
        for (int j = 0; j < 4; ++j) rl[j] = 1.0f / lrun[j];
        const size_t obase = (size_t)(b * SEQ + qt * 64 + w * 16) * DKV;
        #pragma unroll
        for (int n = 0; n < 8; ++n)
            #pragma unroll
            for (int j = 0; j < 4; ++j)
                out[obase + (size_t)(lg * 4 + j) * DKV + n * 16 + lrow] = o[n][j] * rl[j];
    } else {
        const int qg0 = b * SEQ + qt * 64 + w * 16;
        #pragma unroll
        for (int j = 0; j < 4; ++j) {
            int qg = qg0 + lg * 4 + j;
            size_t obase = ((size_t)s * (NB * SEQ) + qg) * DKV;
            #pragma unroll
            for (int n = 0; n < 8; ++n)
                Opart[obase + n * 16 + lrow] = o[n][j];
            if (lrow == 0) {
                Mp[(size_t)s * (NB * SEQ) + qg] = mrun[j];
                Lp[(size_t)s * (NB * SEQ) + qg] = lrun[j];
            }
        }
    }
}

// ---------------- kernel 3: combine split partials ----------------
__global__ __launch_bounds__(256) void combine_kernel(
    const float* __restrict__ Opart, const float* __restrict__ Mp,
    const float* __restrict__ Lp, float* __restrict__ out, int nsplit) {
    int g = blockIdx.x * 256 + threadIdx.x;   // 16384*32 threads
    int r = g >> 5;
    int c0 = (g & 31) * 4;
    float M = -INFINITY;
    for (int s = 0; s < nsplit; ++s) M = fmaxf(M, Mp[(size_t)s * (NB * SEQ) + r]);
    float W = 0.f;
    float4 acc = {0.f, 0.f, 0.f, 0.f};
    for (int s = 0; s < nsplit; ++s) {
        float wgt = __expf(Mp[(size_t)s * (NB * SEQ) + r] - M);
        W += wgt * Lp[(size_t)s * (NB * SEQ) + r];
        float4 v = *(const float4*)(Opart + ((size_t)s * (NB * SEQ) + r) * DKV + c0);
        acc.x += wgt * v.x; acc.y += wgt * v.y; acc.z += wgt * v.z; acc.w += wgt * v.w;
    }
    float rw = 1.0f / W;
    float4 res = {acc.x * rw, acc.y * rw, acc.z * rw, acc.w * rw};
    *(float4*)(out + (size_t)r * DKV + c0) = res;
}

extern "C" void kernel_launch(void* const* d_in, const int* in_sizes, int n_in,
                              void* d_out, int out_size, void* d_ws, size_t ws_size,
                              hipStream_t stream) {
    const float* X  = (const float*)d_in[0];
    const float* Wq = (const float*)d_in[1];
    const float* bq = (const float*)d_in[2];
    const float* Wk = (const float*)d_in[3];
    const float* bk = (const float*)d_in[4];
    const float* Wv = (const float*)d_in[5];
    const float* bv = (const float*)d_in[6];
    float* out = (float*)d_out;

    const size_t nqe = (size_t)NB * SEQ * DKV;            // 2M elements
    _Float16* Qh  = (_Float16*)d_ws;
    _Float16* Kh  = Qh  + nqe;
    _Float16* VTh = Kh  + nqe;
    _Float16* WTh = VTh + nqe;                            // 3*128*1024 f16
    size_t f16_bytes = (3 * nqe + (size_t)3 * 128 * 1024) * sizeof(_Float16);
    f16_bytes = (f16_bytes + 255) & ~(size_t)255;

    // per-split partial cost: O' (NB*SEQ*DKV f32) + m,l (NB*SEQ f32 each)
    size_t per_split = nqe * 4 + (size_t)NB * SEQ * 8;
    size_t avail = (ws_size > f16_bytes) ? ws_size - f16_bytes : 0;
    int nsplit = (avail >= 4 * per_split) ? 4 : (avail >= 2 * per_split) ? 2 : 1;
    int kps = SEQ / nsplit;

    float* Opart = (float*)((char*)d_ws + f16_bytes);
    float* Mp = Opart + (size_t)nsplit * NB * SEQ * DKV;
    float* Lp = Mp + (size_t)nsplit * NB * SEQ;

    prep_wt<<<(3 * 1024 * 128) / 256, 256, 0, stream>>>(Wq, Wk, Wv, WTh);
    qkv_proj<<<(NB * SEQ / 64) * 3, 256, 0, stream>>>(X, bq, bk, bv, WTh, Qh, Kh, VTh);
    attn_kernel<<<NB * nsplit * 64, 256, 0, stream>>>(Qh, Kh, VTh, out, Opart, Mp, Lp,
                                                      nsplit, kps);
    if (nsplit > 1)
        combine_kernel<<<(NB * SEQ * 32) / 256, 256, 0, stream>>>(Opart, Mp, Lp, out, nsplit);
}